// Round 11
// baseline (1325.682 us; speedup 1.0000x reference)
//
#include <hip/hip_runtime.h>
#include <stdint.h>

// MixtureOfSoftmaxes: B=1024, H=4, D=256, V=100000
// out[b,v] = sum_h pi[b,h] * softmax_v(proj[b,h,:]·emb[v,:])
// No-max softmax (|logits| < ~3), base-2 (embF pre-scaled by log2e):
//   pass C: part[vt][m] = sum_{v in vt} exp2(l'); reduce -> w = pi/s
//   pass D: out[b,v] = sum_h w[m]*exp2(l')
// R11: zero-LDS zero-barrier GEMM with BOTH operands in fragment order (projF,
// embF) streamed coalesced from L2 through a depth-4 register ring, prefetch
// distance 3 (~330cyc > L2 latency). No Bf residency -> registers go to the ring.
// Keeps XCD-bijective map + per-wave m-tile stagger + exp2 epilogues.

#define VOCAB 100000
#define NVT 1564   // v-tiles of 64 (covers 100096)
#define VPAD 100096

typedef __attribute__((ext_vector_type(8))) short short8;
typedef __attribute__((ext_vector_type(4))) float f32x4;

__device__ __forceinline__ short f2bf(float f) {
  uint32_t u = __float_as_uint(f);
  u = (u + 0x7FFFu + ((u >> 16) & 1u)) >> 16;
  return (short)u;
}

// ---------------- kernel 1: proj = tanh(x @ proj_mat^T) -> projF (frag order) ---
// frag layout: elem addr = ((((m>>6)*8 + (k>>5))*4 + ((m>>4)&3))*64
//                           + ((k>>3)&3)*16 + (m&15))*8 + (k&7)
// where m = b*4 + (c>>8)  (flat row of [4096][256] view), k = c&255.
__global__ __launch_bounds__(256) void proj_kernel(const float* __restrict__ x,
                                                   const float* __restrict__ pm,
                                                   short* __restrict__ projF) {
  __shared__ float xs[64][36];
  __shared__ float ps[64][36];
  const int tid = threadIdx.x;
  const int tx = tid & 15, ty = tid >> 4;
  const int m0 = blockIdx.y * 64, n0 = blockIdx.x * 64;
  float acc[4][4];
#pragma unroll
  for (int i = 0; i < 4; i++)
#pragma unroll
    for (int j = 0; j < 4; j++) acc[i][j] = 0.f;

  for (int k0 = 0; k0 < 256; k0 += 32) {
    const int r = tid >> 2, c = (tid & 3) * 8;
    *(float4*)&xs[r][c]     = *(const float4*)&x[(m0 + r) * 256 + k0 + c];
    *(float4*)&xs[r][c + 4] = *(const float4*)&x[(m0 + r) * 256 + k0 + c + 4];
    *(float4*)&ps[r][c]     = *(const float4*)&pm[(n0 + r) * 256 + k0 + c];
    *(float4*)&ps[r][c + 4] = *(const float4*)&pm[(n0 + r) * 256 + k0 + c + 4];
    __syncthreads();
#pragma unroll
    for (int kk = 0; kk < 32; kk += 4) {
      float4 xa[4], pb[4];
#pragma unroll
      for (int i = 0; i < 4; i++) xa[i] = *(const float4*)&xs[ty * 4 + i][kk];
#pragma unroll
      for (int j = 0; j < 4; j++) pb[j] = *(const float4*)&ps[tx * 4 + j][kk];
#pragma unroll
      for (int i = 0; i < 4; i++)
#pragma unroll
        for (int j = 0; j < 4; j++)
          acc[i][j] += xa[i].x * pb[j].x + xa[i].y * pb[j].y +
                       xa[i].z * pb[j].z + xa[i].w * pb[j].w;
    }
    __syncthreads();
  }
#pragma unroll
  for (int i = 0; i < 4; i++)
#pragma unroll
    for (int j = 0; j < 4; j++) {
      int b = m0 + ty * 4 + i, c = n0 + tx * 4 + j;
      int m = b * 4 + (c >> 8), k = c & 255;
      size_t addr = ((((size_t)(m >> 6) * 8 + (k >> 5)) * 4 + ((m >> 4) & 3)) * 64 +
                     ((k >> 3) & 3) * 16 + (m & 15)) * 8 + (k & 7);
      projF[addr] = f2bf(tanhf(acc[i][j]));
    }
}

// ---------------- kernel 2: pi = softmax(x @ mix_mat^T)  [1024 x 4] --------------
__global__ __launch_bounds__(256) void pi_kernel(const float* __restrict__ x,
                                                 const float* __restrict__ mm,
                                                 float* __restrict__ pi) {
  int b = blockIdx.x * 256 + threadIdx.x;
  if (b >= 1024) return;
  float acc[4] = {0.f, 0.f, 0.f, 0.f};
  for (int k = 0; k < 256; k += 4) {
    float4 xv = *(const float4*)&x[(size_t)b * 256 + k];
#pragma unroll
    for (int h = 0; h < 4; h++) {
      float4 mv = *(const float4*)&mm[h * 256 + k];
      acc[h] += xv.x * mv.x + xv.y * mv.y + xv.z * mv.z + xv.w * mv.w;
    }
  }
  float mx = fmaxf(fmaxf(acc[0], acc[1]), fmaxf(acc[2], acc[3]));
  float e[4], ssum = 0.f;
#pragma unroll
  for (int h = 0; h < 4; h++) { e[h] = __expf(acc[h] - mx); ssum += e[h]; }
#pragma unroll
  for (int h = 0; h < 4; h++) pi[b * 4 + h] = e[h] / ssum;
}

// ------- kernel 3: embF = bf16(emb * log2e) in B-fragment order, zero-padded ----
// chunk (vt,kt,ni): embF[(((vt*8)+kt)*4+ni)*512 + lane*8 + j] =
//   emb[(vt*64 + ni*16 + (lane&15))*256 + kt*32 + (lane>>4)*8 + j] * log2e
__global__ __launch_bounds__(256) void embF_kernel(const float* __restrict__ emb,
                                                   short* __restrict__ embF) {
  int c8 = blockIdx.x * 256 + threadIdx.x;  // one short8 per thread
  int lane = c8 & 63, ni = (c8 >> 6) & 3, kt = (c8 >> 8) & 7, vt = c8 >> 11;
  int v = vt * 64 + ni * 16 + (lane & 15);
  int k = kt * 32 + ((lane >> 4) & 3) * 8;
  const float C = 1.44269504088896f;  // log2(e): exp(l) == exp2(l*C)
  short8 b8;
  if (v < VOCAB) {
    float4 f0 = *(const float4*)&emb[(size_t)v * 256 + k];
    float4 f1 = *(const float4*)&emb[(size_t)v * 256 + k + 4];
    b8[0] = f2bf(f0.x * C); b8[1] = f2bf(f0.y * C); b8[2] = f2bf(f0.z * C); b8[3] = f2bf(f0.w * C);
    b8[4] = f2bf(f1.x * C); b8[5] = f2bf(f1.y * C); b8[6] = f2bf(f1.z * C); b8[7] = f2bf(f1.w * C);
  } else {
#pragma unroll
    for (int j = 0; j < 8; ++j) b8[j] = 0;
  }
  *(short8*)&embF[(size_t)c8 * 8] = b8;
}

// ---------------- big GEMM: zero-LDS, ring-prefetched A+B, staggered waves ------
// Block = one 64-col v-tile, 4 independent waves = 4 m-quarters (1024 rows each).
// Per kt cluster: prefetch slot kt+3 (4 A + 4 B coalesced dwordx4), 16 MFMA on
// slot kt. Distance-3 prefetch (~330cyc) covers L2 latency; tile-boundary
// prefetches (kt=5..7 -> next tile) keep loads in flight through the epilogue.

#define LOADK(SLOT, MT, KT)                                                               \
  do {                                                                                    \
    const short* at_ = aq + (size_t)(((MT) * 8 + (KT)) * 4) * 512;                        \
    const short* bt_ = bq + (KT) * 2048;                                                  \
    _Pragma("unroll") for (int q = 0; q < 4; ++q)                                         \
        ring[SLOT][q] = *(const short8*)(at_ + q * 512);                                  \
    _Pragma("unroll") for (int q = 0; q < 4; ++q)                                         \
        ring[SLOT][4 + q] = *(const short8*)(bt_ + q * 512);                              \
  } while (0)

template <int MODE>
__global__ __launch_bounds__(256, 2) void mos_gemm(const short* __restrict__ projF,
                                                   const short* __restrict__ embF,
                                                   const float* __restrict__ w,
                                                   float* __restrict__ part,
                                                   float* __restrict__ out) {
  const int tid = threadIdx.x;
  const int lane = tid & 63, wid = tid >> 6;
  const int l15 = lane & 15, l4 = lane >> 4;

  // bijective chunked XCD map over 1564 blocks (8 XCDs: 4x196 + 4x195)
  const int bid = blockIdx.x;
  const int xcd = bid & 7, idx = bid >> 3;
  const int vt = (xcd < 4) ? (xcd * 196 + idx) : (784 + (xcd - 4) * 195 + idx);
  const int v0 = vt * 64;
  const int M0 = wid * 1024;           // wave's m-quarter
  const int mts = (wid * 4 + idx) & 15;  // per-wave m-tile start phase

  const short* aq = projF + (size_t)(M0 >> 6) * 32 * 512 + lane * 8;
  const short* bq = embF + (size_t)vt * 16384 + lane * 8;

  short8 ring[4][8];  // [slot][0..3 = A mi][4..7 = B ni]  (128 VGPR, static idx)
  f32x4 acc[4][4];
#pragma unroll
  for (int i = 0; i < 4; ++i)
#pragma unroll
    for (int j = 0; j < 4; ++j) acc[i][j] = (f32x4){0.f, 0.f, 0.f, 0.f};

  // prologue: fill slots 0..2 with (mts, kt=0..2)
  LOADK(0, mts, 0);
  LOADK(1, mts, 1);
  LOADK(2, mts, 2);

#pragma unroll 1
  for (int it = 0; it < 16; ++it) {
    const int mt = (mts + it) & 15;
    const int mtn = (mts + it + 1) & 15;
#pragma unroll
    for (int kt = 0; kt < 8; ++kt) {
      if (kt < 5) {
        LOADK((kt + 3) & 3, mt, kt + 3);
      } else if (it < 15) {
        LOADK((kt + 3) & 3, mtn, kt - 5);
      }
      __builtin_amdgcn_s_setprio(1);
#pragma unroll
      for (int mi = 0; mi < 4; ++mi)
#pragma unroll
        for (int ni = 0; ni < 4; ++ni)
          acc[mi][ni] = __builtin_amdgcn_mfma_f32_16x16x32_bf16(
              ring[kt & 3][mi], ring[kt & 3][4 + ni], acc[mi][ni], 0, 0, 0);
      __builtin_amdgcn_s_setprio(0);
    }

    // ---- epilogue for m-tile mt (loads for next tile already in flight) ----
    if (MODE == 0) {
#pragma unroll
      for (int mi = 0; mi < 4; ++mi) {
        float p[4] = {0.f, 0.f, 0.f, 0.f};
#pragma unroll
        for (int ni = 0; ni < 4; ++ni) {
          int v = v0 + ni * 16 + l15;
          bool ok = v < VOCAB;
#pragma unroll
          for (int r = 0; r < 4; ++r) {
            float e = exp2f(acc[mi][ni][r]);
            p[r] += ok ? e : 0.f;
          }
          acc[mi][ni] = (f32x4){0.f, 0.f, 0.f, 0.f};
        }
#pragma unroll
        for (int r = 0; r < 4; ++r) {
          p[r] += __shfl_xor(p[r], 1, 64);
          p[r] += __shfl_xor(p[r], 2, 64);
          p[r] += __shfl_xor(p[r], 4, 64);
          p[r] += __shfl_xor(p[r], 8, 64);
        }
        if (l15 == 0) {
          int m = M0 + mt * 64 + mi * 16 + l4 * 4;
          float4 pv = {p[0], p[1], p[2], p[3]};
          *(float4*)(part + (size_t)vt * 4096 + m) = pv;
        }
      }
    } else {
#pragma unroll
      for (int mi = 0; mi < 4; ++mi) {
        int mrow = M0 + mt * 64 + mi * 16 + l4 * 4;
        float4 wv = *(const float4*)&w[mrow];
        size_t brow = (size_t)(mrow >> 2);
#pragma unroll
        for (int ni = 0; ni < 4; ++ni) {
          int v = v0 + ni * 16 + l15;
          float val = wv.x * exp2f(acc[mi][ni][0]) + wv.y * exp2f(acc[mi][ni][1]) +
                      wv.z * exp2f(acc[mi][ni][2]) + wv.w * exp2f(acc[mi][ni][3]);
          if (v < VOCAB) out[brow * VOCAB + v] = val;
          acc[mi][ni] = (f32x4){0.f, 0.f, 0.f, 0.f};
        }
      }
    }
  }
}

// ---------------- reduce partials + w = pi / s ----------------------------------
__global__ __launch_bounds__(256) void reduce_w(const float* __restrict__ part,
                                                const float* __restrict__ pi,
                                                float* __restrict__ w) {
  int m = blockIdx.x * 256 + threadIdx.x;  // 0..4095
  float sum = 0.f;
  for (int c = 0; c < NVT; ++c) sum += part[(size_t)c * 4096 + m];
  w[m] = pi[m] / sum;
}

extern "C" void kernel_launch(void* const* d_in, const int* in_sizes, int n_in,
                              void* d_out, int out_size, void* d_ws, size_t ws_size,
                              hipStream_t stream) {
  const float* x        = (const float*)d_in[0];
  const float* proj_mat = (const float*)d_in[1];
  const float* mix_mat  = (const float*)d_in[2];
  const float* emb      = (const float*)d_in[3];
  float* out = (float*)d_out;

  char* ws = (char*)d_ws;
  short* projF = (short*)ws;                           // bf16 frag-order A, 2 MB
  float* pi    = (float*)(ws + (2u << 20));            // [4096]
  float* w     = (float*)(ws + (2u << 20) + 16384);    // [4096]
  short* embF  = (short*)(ws + (4u << 20));            // bf16 frag-order B, 51.2 MB
  float* part  = (float*)(ws + (4u << 20) + (size_t)NVT * 32768);  // [1564][4096] = 25.6 MB

  dim3 g1(16, 16);
  proj_kernel<<<g1, 256, 0, stream>>>(x, proj_mat, projF);
  pi_kernel<<<4, 256, 0, stream>>>(x, mix_mat, pi);
  embF_kernel<<<NVT * 16384 / 256 / 8, 256, 0, stream>>>(emb, embF);  // 12512 blocks

  mos_gemm<0><<<NVT, 256, 0, stream>>>(projF, embF, nullptr, part, nullptr);
  reduce_w<<<16, 256, 0, stream>>>(part, pi, w);
  mos_gemm<1><<<NVT, 256, 0, stream>>>(projF, embF, w, nullptr, out);
}

// Round 12
// 796.101 us; speedup vs baseline: 1.6652x; 1.6652x over previous
//
#include <hip/hip_runtime.h>
#include <hip/hip_fp16.h>
#include <stdint.h>

// MixtureOfSoftmaxes: B=1024, H=4, D=256, V=100000
// out[b,v] = sum_h pi[b,h] * softmax_v(proj[b,h,:]·emb[v,:])
// No-max softmax (|logits| < ~3), base-2 (embB pre-scaled by log2e).
// R12 (e-store): run the big GEMM ONCE (pass G = R10 structure: zero-LDS,
// Bf register-resident, wave stagger, XCD map). Epilogue stores e=exp2(l') as
// fp16 in fragment-lane order (coalesced 8B/lane; lane's 4 values = the 4 HEADS
// of one b) + per-v-tile partial sums. Then reduce -> w = pi/s, and a pure
// streaming mix pass: out[b,v] = dot(w[b,:], e4). Replaces the 2nd 210-GFLOP
// GEMM with a ~1.2GB HBM stream. Fallback to two-GEMM path if ws too small.

#define VOCAB 100000
#define NVT 1564   // v-tiles of 64 (covers 100096)
#define VPAD 100096
#define ETOT (((size_t)NVT) << 16)   // 8B lane-units in eF = 102,498,304 (820 MB)

typedef __attribute__((ext_vector_type(8))) short short8;
typedef __attribute__((ext_vector_type(4))) float f32x4;

__device__ __forceinline__ short f2bf(float f) {
  uint32_t u = __float_as_uint(f);
  u = (u + 0x7FFFu + ((u >> 16) & 1u)) >> 16;
  return (short)u;
}
__device__ __forceinline__ uint32_t pkh(float a, float b) {
  __half2 h = __floats2half2_rn(a, b);
  return *reinterpret_cast<uint32_t*>(&h);
}

// ---------------- kernel 1: proj = tanh(x @ proj_mat^T) -> projF (frag order) ---
__global__ __launch_bounds__(256) void proj_kernel(const float* __restrict__ x,
                                                   const float* __restrict__ pm,
                                                   short* __restrict__ projF) {
  __shared__ float xs[64][36];
  __shared__ float ps[64][36];
  const int tid = threadIdx.x;
  const int tx = tid & 15, ty = tid >> 4;
  const int m0 = blockIdx.y * 64, n0 = blockIdx.x * 64;
  float acc[4][4];
#pragma unroll
  for (int i = 0; i < 4; i++)
#pragma unroll
    for (int j = 0; j < 4; j++) acc[i][j] = 0.f;

  for (int k0 = 0; k0 < 256; k0 += 32) {
    const int r = tid >> 2, c = (tid & 3) * 8;
    *(float4*)&xs[r][c]     = *(const float4*)&x[(m0 + r) * 256 + k0 + c];
    *(float4*)&xs[r][c + 4] = *(const float4*)&x[(m0 + r) * 256 + k0 + c + 4];
    *(float4*)&ps[r][c]     = *(const float4*)&pm[(n0 + r) * 256 + k0 + c];
    *(float4*)&ps[r][c + 4] = *(const float4*)&pm[(n0 + r) * 256 + k0 + c + 4];
    __syncthreads();
#pragma unroll
    for (int kk = 0; kk < 32; kk += 4) {
      float4 xa[4], pb[4];
#pragma unroll
      for (int i = 0; i < 4; i++) xa[i] = *(const float4*)&xs[ty * 4 + i][kk];
#pragma unroll
      for (int j = 0; j < 4; j++) pb[j] = *(const float4*)&ps[tx * 4 + j][kk];
#pragma unroll
      for (int i = 0; i < 4; i++)
#pragma unroll
        for (int j = 0; j < 4; j++)
          acc[i][j] += xa[i].x * pb[j].x + xa[i].y * pb[j].y +
                       xa[i].z * pb[j].z + xa[i].w * pb[j].w;
    }
    __syncthreads();
  }
#pragma unroll
  for (int i = 0; i < 4; i++)
#pragma unroll
    for (int j = 0; j < 4; j++) {
      int b = m0 + ty * 4 + i, c = n0 + tx * 4 + j;
      int m = b * 4 + (c >> 8), k = c & 255;
      size_t addr = ((((size_t)(m >> 6) * 8 + (k >> 5)) * 4 + ((m >> 4) & 3)) * 64 +
                     ((k >> 3) & 3) * 16 + (m & 15)) * 8 + (k & 7);
      projF[addr] = f2bf(tanhf(acc[i][j]));
    }
}

// ---------------- kernel 2: pi = softmax(x @ mix_mat^T)  [1024 x 4] --------------
__global__ __launch_bounds__(256) void pi_kernel(const float* __restrict__ x,
                                                 const float* __restrict__ mm,
                                                 float* __restrict__ pi) {
  int b = blockIdx.x * 256 + threadIdx.x;
  if (b >= 1024) return;
  float acc[4] = {0.f, 0.f, 0.f, 0.f};
  for (int k = 0; k < 256; k += 4) {
    float4 xv = *(const float4*)&x[(size_t)b * 256 + k];
#pragma unroll
    for (int h = 0; h < 4; h++) {
      float4 mv = *(const float4*)&mm[h * 256 + k];
      acc[h] += xv.x * mv.x + xv.y * mv.y + xv.z * mv.z + xv.w * mv.w;
    }
  }
  float mx = fmaxf(fmaxf(acc[0], acc[1]), fmaxf(acc[2], acc[3]));
  float e[4], ssum = 0.f;
#pragma unroll
  for (int h = 0; h < 4; h++) { e[h] = __expf(acc[h] - mx); ssum += e[h]; }
#pragma unroll
  for (int h = 0; h < 4; h++) pi[b * 4 + h] = e[h] / ssum;
}

// ------- kernel 3: embB = bf16(emb * log2e), zero-padded to VPAD rows -----------
__global__ __launch_bounds__(256) void embB_kernel(const float* __restrict__ emb,
                                                   short* __restrict__ embB) {
  size_t i = ((size_t)blockIdx.x * 256 + threadIdx.x) * 8;
  size_t row = i >> 8;
  const float C = 1.44269504088896f;  // log2(e): exp(l) == exp2(l*C)
  short8 b8;
  if (row < VOCAB) {
    float4 f0 = *(const float4*)&emb[i];
    float4 f1 = *(const float4*)&emb[i + 4];
    b8[0] = f2bf(f0.x * C); b8[1] = f2bf(f0.y * C); b8[2] = f2bf(f0.z * C); b8[3] = f2bf(f0.w * C);
    b8[4] = f2bf(f1.x * C); b8[5] = f2bf(f1.y * C); b8[6] = f2bf(f1.z * C); b8[7] = f2bf(f1.w * C);
  } else {
#pragma unroll
    for (int j = 0; j < 8; ++j) b8[j] = 0;
  }
  *(short8*)&embB[i] = b8;
}

// ---------------- big GEMM (R10 structure) + e-store ----------------------------
// Block = one 64-col v-tile, 4 independent waves = 4 m-quarters (1024 rows each).
// MODE 0: partial sums (+ optional fp16 e-store, EST=1); MODE 1: mixture output.

#define MFMA16(AF, KT)                                                                    \
  __builtin_amdgcn_s_setprio(1);                                                          \
  _Pragma("unroll") for (int mi = 0; mi < 4; ++mi)                                        \
      _Pragma("unroll") for (int ni = 0; ni < 4; ++ni)                                    \
          acc[mi][ni] = __builtin_amdgcn_mfma_f32_16x16x32_bf16(AF[mi], Bf[ni][KT],       \
                                                                acc[mi][ni], 0, 0, 0);    \
  __builtin_amdgcn_s_setprio(0);

template <int MODE, int EST>
__global__ __launch_bounds__(256, 2) void mos_gemm(const short* __restrict__ projF,
                                                   const short* __restrict__ embB_s,
                                                   const float* __restrict__ w,
                                                   float* __restrict__ part,
                                                   char* __restrict__ eF,
                                                   float* __restrict__ out) {
  const int tid = threadIdx.x;
  const int lane = tid & 63, wid = tid >> 6;
  const int l15 = lane & 15, l4 = lane >> 4;

  // bijective chunked XCD map over 1564 blocks (8 XCDs: 4x196 + 4x195)
  const int bid = blockIdx.x;
  const int xcd = bid & 7, idx = bid >> 3;
  const int vt = (xcd < 4) ? (xcd * 196 + idx) : (784 + (xcd - 4) * 195 + idx);
  const int v0 = vt * 64;
  const int M0 = wid * 1024;             // wave's m-quarter
  const int mts = (wid * 4 + idx) & 15;  // per-wave m-tile start phase

  // ---- B fragments for full K=256, register-resident (128 VGPR) ----
  short8 Bf[4][8];
  {
    const short* bbase = embB_s + (size_t)(v0 + l15) * 256 + l4 * 8;
#pragma unroll
    for (int ni = 0; ni < 4; ++ni)
#pragma unroll
      for (int kt = 0; kt < 8; ++kt)
        Bf[ni][kt] = *(const short8*)(bbase + ni * 4096 + kt * 32);
  }

  f32x4 acc[4][4];
#pragma unroll
  for (int i = 0; i < 4; ++i)
#pragma unroll
    for (int j = 0; j < 4; ++j) acc[i][j] = (f32x4){0.f, 0.f, 0.f, 0.f};

  const short* aq = projF + (size_t)(M0 >> 6) * 32 * 512 + lane * 8;
  const short* ap = aq + mts * 16384;
  short8 aA[4], aB[4];
#pragma unroll
  for (int mi = 0; mi < 4; ++mi) aA[mi] = *(const short8*)(ap + mi * 512);

#pragma unroll 1
  for (int it = 0; it < 16; ++it) {
    const int mt = (mts + it) & 15;
    ap = aq + mt * 16384;
#pragma unroll
    for (int kt = 0; kt < 8; kt += 2) {
#pragma unroll
      for (int mi = 0; mi < 4; ++mi)
        aB[mi] = *(const short8*)(ap + (kt + 1) * 2048 + mi * 512);
      MFMA16(aA, kt);
#pragma unroll
      for (int mi = 0; mi < 4; ++mi)
        aA[mi] = *(const short8*)(ap + (kt + 2) * 2048 + mi * 512);
      MFMA16(aB, kt + 1);
    }
    if (mt == 15 && it < 15) {
#pragma unroll
      for (int mi = 0; mi < 4; ++mi) aA[mi] = *(const short8*)(aq + mi * 512);
    }

    // ---- epilogue for m-tile mt ----
    if (MODE == 0) {
#pragma unroll
      for (int mi = 0; mi < 4; ++mi) {
        float p[4] = {0.f, 0.f, 0.f, 0.f};
#pragma unroll
        for (int ni = 0; ni < 4; ++ni) {
          int v = v0 + ni * 16 + l15;
          bool ok = v < VOCAB;
          float er[4];
#pragma unroll
          for (int r = 0; r < 4; ++r) er[r] = exp2f(acc[mi][ni][r]);
          if (EST) {
            // lane's 4 values = 4 heads of one b; coalesced 8B/lane
            size_t chunk = ((((size_t)vt * 4 + wid) * 16 + mt) * 4 + mi) * 4 + ni;
            uint2 q = {pkh(er[0], er[1]), pkh(er[2], er[3])};
            *(uint2*)(eF + chunk * 512 + lane * 8) = q;
          }
#pragma unroll
          for (int r = 0; r < 4; ++r) p[r] += ok ? er[r] : 0.f;
          acc[mi][ni] = (f32x4){0.f, 0.f, 0.f, 0.f};
        }
#pragma unroll
        for (int r = 0; r < 4; ++r) {
          p[r] += __shfl_xor(p[r], 1, 64);
          p[r] += __shfl_xor(p[r], 2, 64);
          p[r] += __shfl_xor(p[r], 4, 64);
          p[r] += __shfl_xor(p[r], 8, 64);
        }
        if (l15 == 0) {
          int m = M0 + mt * 64 + mi * 16 + l4 * 4;
          float4 pv = {p[0], p[1], p[2], p[3]};
          *(float4*)(part + (size_t)vt * 4096 + m) = pv;
        }
      }
    } else {
#pragma unroll
      for (int mi = 0; mi < 4; ++mi) {
        int mrow = M0 + mt * 64 + mi * 16 + l4 * 4;
        float4 wv = *(const float4*)&w[mrow];
        size_t brow = (size_t)(mrow >> 2);
#pragma unroll
        for (int ni = 0; ni < 4; ++ni) {
          int v = v0 + ni * 16 + l15;
          float val = wv.x * exp2f(acc[mi][ni][0]) + wv.y * exp2f(acc[mi][ni][1]) +
                      wv.z * exp2f(acc[mi][ni][2]) + wv.w * exp2f(acc[mi][ni][3]);
          if (v < VOCAB) out[brow * VOCAB + v] = val;
          acc[mi][ni] = (f32x4){0.f, 0.f, 0.f, 0.f};
        }
      }
    }
  }
}

// ---------------- reduce partials + w = pi / s ----------------------------------
__global__ __launch_bounds__(256) void reduce_w(const float* __restrict__ part,
                                                const float* __restrict__ pi,
                                                float* __restrict__ w) {
  int m = blockIdx.x * 256 + threadIdx.x;  // 0..4095
  float sum = 0.f;
  for (int c = 0; c < NVT; ++c) sum += part[(size_t)c * 4096 + m];
  w[m] = pi[m] / sum;
}

// ---------------- mix: out[b,v] = dot(w[b,:], e4)  (pure streaming) -------------
__global__ __launch_bounds__(256) void mix_kernel(const char* __restrict__ eF,
                                                  const float* __restrict__ w,
                                                  float* __restrict__ out) {
  const size_t stride = (size_t)gridDim.x * 256;
  for (size_t u = (size_t)blockIdx.x * 256 + threadIdx.x; u < ETOT; u += stride) {
    uint2 q = *(const uint2*)(eF + u * 8);
    int lane = (int)(u & 63);
    int ni = (int)((u >> 6) & 3), mi = (int)((u >> 8) & 3);
    int mt = (int)((u >> 10) & 15), mq = (int)((u >> 14) & 3);
    int vt = (int)(u >> 16);
    int v = vt * 64 + ni * 16 + (lane & 15);
    int b = mq * 256 + mt * 16 + mi * 4 + (lane >> 4);
    __half2 h0 = *reinterpret_cast<__half2*>(&q.x);
    __half2 h1 = *reinterpret_cast<__half2*>(&q.y);
    float4 wv = *(const float4*)&w[b * 4];
    float val = wv.x * __low2float(h0) + wv.y * __high2float(h0) +
                wv.z * __low2float(h1) + wv.w * __high2float(h1);
    if (v < VOCAB) out[(size_t)b * VOCAB + v] = val;
  }
}

extern "C" void kernel_launch(void* const* d_in, const int* in_sizes, int n_in,
                              void* d_out, int out_size, void* d_ws, size_t ws_size,
                              hipStream_t stream) {
  const float* x        = (const float*)d_in[0];
  const float* proj_mat = (const float*)d_in[1];
  const float* mix_mat  = (const float*)d_in[2];
  const float* emb      = (const float*)d_in[3];
  float* out = (float*)d_out;

  char* ws = (char*)d_ws;
  short* projF = (short*)ws;                           // bf16 frag-order A, 2 MB
  float* pi    = (float*)(ws + (2u << 20));            // [4096]
  float* w     = (float*)(ws + (2u << 20) + 16384);    // [4096]
  short* embB  = (short*)(ws + (4u << 20));            // bf16 [100096][256] = 48.9 MB
  float* part  = (float*)(ws + (4u << 20) + (size_t)VPAD * 512);  // [1564][4096] = 25.6 MB
  char*  eF    = ws + (88u << 20);                     // fp16 e, 820 MB
  const size_t need = ((size_t)88 << 20) + ETOT * 8;

  dim3 g1(16, 16);
  proj_kernel<<<g1, 256, 0, stream>>>(x, proj_mat, projF);
  pi_kernel<<<4, 256, 0, stream>>>(x, mix_mat, pi);
  embB_kernel<<<VPAD / 8, 256, 0, stream>>>(emb, embB);

  if (ws_size >= need) {
    // e-store path: GEMM once, then stream the mixture
    mos_gemm<0, 1><<<NVT, 256, 0, stream>>>(projF, embB, nullptr, part, eF, nullptr);
    reduce_w<<<16, 256, 0, stream>>>(part, pi, w);
    mix_kernel<<<4096, 256, 0, stream>>>(eF, w, out);
  } else {
    // fallback: two-GEMM path (R10)
    mos_gemm<0, 0><<<NVT, 256, 0, stream>>>(projF, embB, nullptr, part, nullptr, nullptr);
    reduce_w<<<16, 256, 0, stream>>>(part, pi, w);
    mos_gemm<1, 0><<<NVT, 256, 0, stream>>>(projF, embB, w, nullptr, nullptr, out);
  }
}